// Round 7
// baseline (345.934 us; speedup 1.0000x reference)
//
#include <hip/hip_runtime.h>

#define NB 128          // blocks; each handles TWO batch elements
#define NL 512
#define NI 32
#define NH 16
#define NG 64
#define SIGD 4368
#define HS 516          // h row stride in LDS floats (mult of 4 for b128; 2-way bank = free)

__device__ __forceinline__ float RL(float v, int lane) {
  return __builtin_bit_cast(float, __builtin_amdgcn_readlane(__builtin_bit_cast(int, v), lane));
}
template<int CTRL>
__device__ __forceinline__ float QB(float v) {
  // quad_perm broadcast within each 4-lane quad (VALU DPP, no LDS)
  return __builtin_bit_cast(float, __builtin_amdgcn_update_dpp(
      0, __builtin_bit_cast(int, v), CTRL, 0xF, 0xF, true));
}

// 2-batch-per-block design. Phase 0: xw for both batches -> GLOBAL workspace
// (pre-scaled by K_g). Phase A: wave0 runs BOTH batches' LSTM chains
// time-interleaved (independent dataflow fills each chain's latency stalls;
// weights shared; h burst-written to LDS, one prog for both). Phase B: waves
// 1-6 stream signature segments against prog (A: waves 7,1,2,3 / B: 6,4,5).
// Phase C: waves 7 and 6 are per-batch prefix combiners via slot+want/have
// (proven round-3 machinery, now with boundary h read directly from LDS).
// Phase D: FC, 4 waves per batch.
__global__ __launch_bounds__(512, 1) void k_main(const float* __restrict__ X,
    const float* __restrict__ Wih, const float* __restrict__ bih,
    const float* __restrict__ bhh, const float* __restrict__ Whh,
    const float* __restrict__ fcw, const float* __restrict__ fcb,
    float* __restrict__ out, float* __restrict__ xws) {
  __shared__ __align__(16) float hA[NH * HS];     // 33,024 B
  __shared__ __align__(16) float hB[NH * HS];     // 33,024 B
  __shared__ __align__(16) float slotA[4352];     // 17,408 B
  __shared__ __align__(16) float slotB[4352];     // 17,408 B
  __shared__ __align__(16) float sigA[SIGD];      // 17,472 B
  __shared__ __align__(16) float sigB[SIGD];      // 17,472 B
  __shared__ float red[80];
  __shared__ int prog, wantA, haveA, wantB, haveB;
  int tid = threadIdx.x;
  int wv = tid >> 6;
  int ln = tid & 63;
  int b = blockIdx.x;

  if (tid == 0) { prog = -1; wantA = 0; haveA = 0; wantB = 0; haveB = 0; }

  // ---- Phase 0: xw[g][t] (pre-scaled) for BOTH batches -> global workspace.
  {
    const float Kg = (ln >= 32 && ln < 48) ? 2.885390082f : -1.442695041f;
    float w2[NI];
#pragma unroll
    for (int i = 0; i < 8; ++i) {
      float4 v = *(const float4*)(Wih + ln * NI + 4 * i);
      w2[4*i+0] = v.x; w2[4*i+1] = v.y; w2[4*i+2] = v.z; w2[4*i+3] = v.w;
    }
    float bias = bih[ln] + bhh[ln];
#pragma unroll
    for (int bb = 0; bb < 2; ++bb) {
      const float* xb = X + (size_t)(2 * b + bb) * NL * NI;
      float* xg = xws + (size_t)b * (2 * NG * NL) + bb * NG * NL + ln * NL;
      for (int t0 = 64 * wv; t0 < 64 * (wv + 1); t0 += 4) {
        float o4[4];
#pragma unroll
        for (int s = 0; s < 4; ++s) {
          const float4* xr = (const float4*)(xb + (t0 + s) * NI);
          float x0 = bias, x1 = 0.f, x2 = 0.f, x3 = 0.f;
#pragma unroll
          for (int i = 0; i < 8; ++i) {
            float4 xv = xr[i];
            x0 += xv.x * w2[4*i+0]; x1 += xv.y * w2[4*i+1];
            x2 += xv.z * w2[4*i+2]; x3 += xv.w * w2[4*i+3];
          }
          o4[s] = Kg * ((x0 + x1) + (x2 + x3));
        }
        float4 v; v.x = o4[0]; v.y = o4[1]; v.z = o4[2]; v.w = o4[3];
        *(float4*)(xg + t0) = v;
      }
    }
  }
  __syncthreads();   // barrier drains vmcnt -> xw visible via this XCD's L2

  // ---- Phase A (wave 0): dual-batch LSTM, chains interleaved per step.
  if (wv == 0) {
    __asm__ __volatile__("s_setprio 3");
    const int q = ln & 3;
    const int j = ln >> 2;
    const int gmem = q * 16 + j;
    const bool isg = (q == 2);
    const float Kg = isg ? 2.885390082f : -1.442695041f;
    const float CT = 2.885390082f;
    const float Av = isg ? -2.0f : (q == 0 ? CT : 1.0f);
    const float Bv = isg ? 1.0f : 0.0f;
    float w[NH];                               // K-scaled W_hh row (shared A/B)
#pragma unroll
    for (int qq = 0; qq < 4; ++qq) {
      float4 v = *(const float4*)(Whh + gmem * NH + 4 * qq);
      w[4*qq+0] = Kg*v.x; w[4*qq+1] = Kg*v.y; w[4*qq+2] = Kg*v.z; w[4*qq+3] = Kg*v.w;
    }
    const float* xta = xws + (size_t)b * (2 * NG * NL) + gmem * NL;
    const float* xtb = xta + NG * NL;
    float* hdA = hA + j * HS + 4 * q;
    float* hdB = hB + j * HS + 4 * q;
    float4 xqA[4], xqB[4];                     // 16 steps of xval in flight, each batch
#pragma unroll
    for (int i = 0; i < 4; ++i) { xqA[i] = *(const float4*)(xta + 4 * i);
                                  xqB[i] = *(const float4*)(xtb + 4 * i); }
    float csA = 0.f, hvA = 0.f, csB = 0.f, hvB = 0.f;
    float hstA[4] = {0.f,0.f,0.f,0.f}, hstB[4] = {0.f,0.f,0.f,0.f};
    for (int tb = 0; tb < NL; tb += 16) {
#pragma unroll
      for (int k = 0; k < 16; ++k) {
        int t = tb + k;
        float hsA[16], hsB[16];
#pragma unroll
        for (int u = 0; u < 16; ++u) hsA[u] = RL(hvA, 4 * u);
#pragma unroll
        for (int u = 0; u < 16; ++u) hsB[u] = RL(hvB, 4 * u);
        float xvA = ((const float*)xqA)[k];
        float xvB = ((const float*)xqB)[k];
        if ((k & 3) == 3 && t + 16 < NL) {
          xqA[k >> 2] = *(const float4*)(xta + (t + 13));
          xqB[k >> 2] = *(const float4*)(xtb + (t + 13));
        }
        float aA0 = xvA, aA1 = 0.f, aA2 = 0.f, aA3 = 0.f;
        float aB0 = xvB, aB1 = 0.f, aB2 = 0.f, aB3 = 0.f;
#pragma unroll
        for (int u = 0; u < 4; ++u) {
          aA0 += hsA[4*u+0] * w[4*u+0]; aB0 += hsB[4*u+0] * w[4*u+0];
          aA1 += hsA[4*u+1] * w[4*u+1]; aB1 += hsB[4*u+1] * w[4*u+1];
          aA2 += hsA[4*u+2] * w[4*u+2]; aB2 += hsB[4*u+2] * w[4*u+2];
          aA3 += hsA[4*u+3] * w[4*u+3]; aB3 += hsB[4*u+3] * w[4*u+3];
        }
        float accA = (aA0 + aA1) + (aA2 + aA3);
        float accB = (aB0 + aB1) + (aB2 + aB3);
        float eA = __builtin_amdgcn_exp2f(accA);
        float eB = __builtin_amdgcn_exp2f(accB);
        float rA = __builtin_amdgcn_rcpf(1.0f + eA);
        float rB = __builtin_amdgcn_rcpf(1.0f + eB);
        float valA = __builtin_fmaf(Av, rA, Bv);
        float valB = __builtin_fmaf(Av, rB, Bv);
        float ivA = QB<0x00>(valA), ivB = QB<0x00>(valB);
        float fvA = QB<0x55>(valA), fvB = QB<0x55>(valB);
        float gvA = QB<0xAA>(valA), gvB = QB<0xAA>(valB);
        float ovA = QB<0xFF>(valA), ovB = QB<0xFF>(valB);
        csA = __builtin_fmaf(fvA, csA, ivA * gvA);
        csB = __builtin_fmaf(fvB, csB, ivB * gvB);
        float e2A = __builtin_amdgcn_exp2f(csA);
        float e2B = __builtin_amdgcn_exp2f(csB);
        float tcA = __builtin_fmaf(-2.0f, __builtin_amdgcn_rcpf(1.0f + e2A), 1.0f);
        float tcB = __builtin_fmaf(-2.0f, __builtin_amdgcn_rcpf(1.0f + e2B), 1.0f);
        hvA = ovA * tcA;
        hvB = ovB * tcB;
        hstA[k & 3] = (q == (k >> 2)) ? hvA : hstA[k & 3];
        hstB[k & 3] = (q == (k >> 2)) ? hvB : hstB[k & 3];
      }
      float4 hva4; hva4.x = hstA[0]; hva4.y = hstA[1]; hva4.z = hstA[2]; hva4.w = hstA[3];
      float4 hvb4; hvb4.x = hstB[0]; hvb4.y = hstB[1]; hvb4.z = hstB[2]; hvb4.w = hstB[3];
      *(float4*)(hdA + tb) = hva4;
      *(float4*)(hdB + tb) = hvb4;
      __asm__ __volatile__("" ::: "memory");
      if (ln == 0) *(volatile int*)&prog = tb + 15;
    }
    __asm__ __volatile__("s_setprio 0");
  } else {
    // ---- Phase B: streaming signature segment for this wave.
    // A: waves 7(prefix,[0,160]) 1([160,300]) 2([300,420]) 3([420,511])
    // B: waves 6(prefix,[0,200]) 4([200,380]) 5([380,511])
    const float* hb; float* sb;
    volatile int* wantp; volatile int* havep;
    int sidx, ts, te;
    if (wv == 1 || wv == 2 || wv == 3 || wv == 7) {
      hb = hA; sb = slotA; wantp = &wantA; havep = &haveA;
    } else {
      hb = hB; sb = slotB; wantp = &wantB; havep = &haveB;
    }
    switch (wv) {
      case 7: sidx = 0; ts = 0;   te = 160; break;
      case 1: sidx = 1; ts = 160; te = 300; break;
      case 2: sidx = 2; ts = 300; te = 420; break;
      case 3: sidx = 3; ts = 420; te = 511; break;
      case 6: sidx = 0; ts = 0;   te = 200; break;
      case 4: sidx = 1; ts = 200; te = 380; break;
      default: sidx = 2; ts = 380; te = 511; break;   // wv == 5
    }
    const int bi = ln & 15;
    const int hi = ln >> 4;

    float s3[4][16];
    float s2[4] = {0.f, 0.f, 0.f, 0.f};
#pragma unroll
    for (int m = 0; m < 4; ++m)
#pragma unroll
      for (int cc = 0; cc < 16; ++cc) s3[m][cc] = 0.f;

    int avail;
    while ((avail = *(volatile int*)&prog) < ts) __builtin_amdgcn_s_sleep(2);
    __asm__ __volatile__("" ::: "memory");

    float hc16A[16], hc16B[16];
    float hAb, hBb;
    float hAa[4], hBa[4], h0a[4];
#pragma unroll
    for (int cc = 0; cc < 16; ++cc) hc16A[cc] = hb[cc * HS + ts];   // uniform reads
    hAb = hb[bi * HS + ts];
#pragma unroll
    for (int m = 0; m < 4; ++m) { hAa[m] = hb[(4 * m + hi) * HS + ts]; h0a[m] = hAa[m]; }

    auto SSTEP = [&](float (&hc16)[16], float& hcb, float (&hca)[4],
                     float (&hn16)[16], float& hnb, float (&hna)[4], int tn) {
#pragma unroll
      for (int cc = 0; cc < 16; ++cc) hn16[cc] = hb[cc * HS + tn];
      hnb = hb[bi * HS + tn];
      float d[16];
#pragma unroll
      for (int cc = 0; cc < 16; ++cc) d[cc] = hn16[cc] - hc16[cc];
      float db = hnb - hcb;
      float P[4];
#pragma unroll
      for (int m = 0; m < 4; ++m) {
        hna[m] = hb[(4 * m + hi) * HS + tn];
        float da = hna[m] - hca[m];
        float s1 = hca[m] - h0a[m];                      // S1[a] pre-increment (telescoping)
        P[m] = s2[m] + db * (0.5f * s1 + 0.166666666667f * da);
        s2[m] += db * (s1 + 0.5f * da);                  // S2 += e2 + S1(x)e1
      }
#pragma unroll
      for (int m = 0; m < 4; ++m)
#pragma unroll
        for (int cc = 0; cc < 16; ++cc)
          s3[m][cc] += P[m] * d[cc];                     // S3 += e3 + S2(x)e1 + S1(x)e2
    };

    {
      int t = ts;
      for (; t + 2 <= te; t += 2) {
        int tn2 = t + 2;
        if (tn2 > avail) {
          while ((avail = *(volatile int*)&prog) < tn2) __builtin_amdgcn_s_sleep(2);
          __asm__ __volatile__("" ::: "memory");
        }
        SSTEP(hc16A, hAb, hAa, hc16B, hBb, hBa, t + 1);
        SSTEP(hc16B, hBb, hBa, hc16A, hAb, hAa, t + 2);
      }
      if (t < te) {
        if (te > avail) {
          while ((avail = *(volatile int*)&prog) < te) __builtin_amdgcn_s_sleep(2);
          __asm__ __volatile__("" ::: "memory");
        }
        SSTEP(hc16A, hAb, hAa, hc16B, hBb, hBa, t + 1);
      }
    }

    // ---- Phase C: prefix combine per batch.
    auto COMB = [&](const float* hb2, const float* sb2, int ae_, int be_) {
      float s1b[16];
#pragma unroll
      for (int cc = 0; cc < 16; ++cc)
        s1b[cc] = hb2[cc * HS + be_] - hb2[cc * HS + ae_];
      float s1bb = hb2[bi * HS + be_] - hb2[bi * HS + ae_];
      float s1aa[4];
#pragma unroll
      for (int m = 0; m < 4; ++m) {
        int a = 4 * m + hi;
        s1aa[m] = hb2[a * HS + ae_] - hb2[a * HS + 0];
      }
      float row[16];
#pragma unroll
      for (int cc = 0; cc < 16; ++cc) row[cc] = sb2[bi * 16 + cc];
#pragma unroll
      for (int m = 0; m < 4; ++m) {
        float s2bo = sb2[64 * m + ln];
#pragma unroll
        for (int cc = 0; cc < 16; ++cc)
          s3[m][cc] += sb2[256 + 64 * ln + ((m * 16 + cc) ^ (ln & 31))]
                     + s2[m] * s1b[cc] + s1aa[m] * row[cc];   // uses OLD s2 (S2a)
        s2[m] += s2bo + s1aa[m] * s1bb;
      }
    };
    auto EMIT = [&](float* sg, const float* hb2) {
      if (ln < 16) sg[ln] = hb2[ln * HS + 511] - hb2[ln * HS + 0];   // S1
#pragma unroll
      for (int m = 0; m < 4; ++m) sg[16 + 64 * m + ln] = s2[m];      // S2: a*16+b
#pragma unroll
      for (int m = 0; m < 4; ++m) {                                  // S3: a*256+b*16+c
#pragma unroll
        for (int qq = 0; qq < 4; ++qq) {
          float4 v;
          v.x = s3[m][4*qq+0]; v.y = s3[m][4*qq+1]; v.z = s3[m][4*qq+2]; v.w = s3[m][4*qq+3];
          *(float4*)(sg + 272 + 1024 * m + 256 * hi + 16 * bi + 4 * qq) = v;
        }
      }
    };

    if (wv == 7) {
      if (ln == 0) *(volatile int*)&wantA = 1;
      while (*(volatile int*)&haveA != 1) __builtin_amdgcn_s_sleep(8);
      __asm__ __volatile__("" ::: "memory");
      COMB(hA, slotA, 160, 300);
      if (ln == 0) *(volatile int*)&wantA = 2;
      while (*(volatile int*)&haveA != 2) __builtin_amdgcn_s_sleep(8);
      __asm__ __volatile__("" ::: "memory");
      COMB(hA, slotA, 300, 420);
      if (ln == 0) *(volatile int*)&wantA = 3;
      while (*(volatile int*)&haveA != 3) __builtin_amdgcn_s_sleep(8);
      __asm__ __volatile__("" ::: "memory");
      COMB(hA, slotA, 420, 511);
      EMIT(sigA, hA);
    } else if (wv == 6) {
      if (ln == 0) *(volatile int*)&wantB = 1;
      while (*(volatile int*)&haveB != 1) __builtin_amdgcn_s_sleep(8);
      __asm__ __volatile__("" ::: "memory");
      COMB(hB, slotB, 200, 380);
      if (ln == 0) *(volatile int*)&wantB = 2;
      while (*(volatile int*)&haveB != 2) __builtin_amdgcn_s_sleep(8);
      __asm__ __volatile__("" ::: "memory");
      COMB(hB, slotB, 380, 511);
      EMIT(sigB, hB);
    } else {
      // producer: wait my turn, publish chunk state into my batch's slot
      while (*(volatile int*)wantp != sidx) __builtin_amdgcn_s_sleep(8);
      __asm__ __volatile__("" ::: "memory");
#pragma unroll
      for (int m = 0; m < 4; ++m) sb[64 * m + ln] = s2[m];   // index == a*16+b
#pragma unroll
      for (int m = 0; m < 4; ++m)
#pragma unroll
        for (int cc = 0; cc < 16; ++cc)
          sb[256 + 64 * ln + ((m * 16 + cc) ^ (ln & 31))] = s3[m][cc];
      __asm__ __volatile__("s_waitcnt lgkmcnt(0)" ::: "memory");
      if (ln == 0) *(volatile int*)havep = sidx;
    }
  }
  __syncthreads();

  // ---- Phase D: FC for both batches. Waves 0-3 -> batch A, 4-7 -> batch B.
  {
    const float* sg = (wv < 4) ? sigA : sigB;
    const int wb = wv & 3;
    float acc[10];
#pragma unroll
    for (int o = 0; o < 10; ++o) acc[o] = 0.f;
    for (int k = wb * 64 + ln; k < SIGD; k += 256) {
      float s = sg[k];
#pragma unroll
      for (int o = 0; o < 10; ++o) acc[o] += s * fcw[o * SIGD + k];
    }
#pragma unroll
    for (int o = 0; o < 10; ++o) {
      float v = acc[o];
#pragma unroll
      for (int off = 32; off > 0; off >>= 1) v += __shfl_down(v, off);
      if (ln == 0) red[wv * 10 + o] = v;
    }
    __syncthreads();
    if (tid < 10) {
      float s = fcb[tid];
#pragma unroll
      for (int w8 = 0; w8 < 4; ++w8) s += red[w8 * 10 + tid];
      out[(2 * b) * 10 + tid] = s;
    } else if (tid >= 64 && tid < 74) {
      int o = tid - 64;
      float s = fcb[o];
#pragma unroll
      for (int w8 = 4; w8 < 8; ++w8) s += red[w8 * 10 + o];
      out[(2 * b + 1) * 10 + o] = s;
    }
  }
}

extern "C" void kernel_launch(void* const* d_in, const int* in_sizes, int n_in,
                              void* d_out, int out_size, void* d_ws, size_t ws_size,
                              hipStream_t stream) {
  const float* X   = (const float*)d_in[0];
  const float* Wih = (const float*)d_in[1];
  const float* Whh = (const float*)d_in[2];
  const float* bih = (const float*)d_in[3];
  const float* bhh = (const float*)d_in[4];
  const float* fcw = (const float*)d_in[5];
  const float* fcb = (const float*)d_in[6];
  float* out = (float*)d_out;
  // workspace: xw for 256 batches = 128 blocks * 2 * 64 * 512 floats = 33.5 MB
  k_main<<<NB, 512, 0, stream>>>(X, Wih, bih, bhh, Whh, fcw, fcb, out, (float*)d_ws);
}

// Round 8
// 189.188 us; speedup vs baseline: 1.8285x; 1.8285x over previous
//
#include <hip/hip_runtime.h>

#define NB 256
#define NL 512
#define NI 32
#define NH 16
#define NG 64
#define SIGD 4368
#define XS 516   // xwT row stride (floats): pad -> strided access lands 2-way (free)

template<int CTRL>
__device__ __forceinline__ float QB(float v) {
  // quad_perm broadcast within each 4-lane quad (VALU DPP, no LDS)
  return __builtin_bit_cast(float, __builtin_amdgcn_update_dpp(
      0, __builtin_bit_cast(int, v), CTRL, 0xF, 0xF, true));
}
__device__ __forceinline__ int segc(int k) {
  // segment cuts: seg0=[0,76] (prefix wave), seg1..6 = 72 steps (waves 1-6),
  // seg7=[504,511] (wave0 after LSTM, solo rate but only 7 steps)
  switch (k) {
    case 1: return 76;  case 2: return 148; case 3: return 220; case 4: return 292;
    case 5: return 364; case 6: return 436; case 7: return 504; case 8: return 511;
    default: return 0;
  }
}

// Round-3 structure (proven 128us) with the LSTM broadcast rebuilt:
// h[t-1] is broadcast to all 64 lanes via 4 conflict-free ds_read_b128 from a
// contiguous 16-float hcur copy, replacing 16 v_readlane per step (-20% instrs
// on the issue-bound serial wave). One dual-role ds_write_b32 per step: quad
// lane q0 -> hcur[j], q1 -> h column xwT[j*XS+t] (Phase B input), q2/3 ->
// scratch. DS ops are per-wave in-order, so step t's reads see step t-1's
// write without barriers. Everything else identical to round 3.
__global__ __launch_bounds__(512, 1) void k_main(const float* __restrict__ X,
    const float* __restrict__ Wih, const float* __restrict__ bih,
    const float* __restrict__ bhh, const float* __restrict__ Whh,
    const float* __restrict__ fcw, const float* __restrict__ fcb,
    float* __restrict__ out) {
  __shared__ __align__(16) float xwT[NG * XS];    // 132,096 B
  __shared__ __align__(16) float slot[4352];      // 17,408 B (one chunk state)
  __shared__ __align__(16) float hcur[48];        // [0,16) h copy; [16,48) scratch
  __shared__ __align__(16) float red[80];
  __shared__ int prog;
  __shared__ int want;
  __shared__ int have;
  int tid = threadIdx.x;
  int wv = tid >> 6;
  int ln = tid & 63;
  int b = blockIdx.x;

  if (tid == 0) { prog = -1; want = 0; have = 0; }

  // ---- Phase 0: xwT[g][t] = K_g * (X[b,t,:]·W_ih[g,:] + b_ih[g] + b_hh[g]).
  {
    const float Kg = (ln >= 32 && ln < 48) ? 2.885390082f : -1.442695041f;
    float w2[NI];
#pragma unroll
    for (int i = 0; i < 8; ++i) {
      float4 v = *(const float4*)(Wih + ln * NI + 4 * i);
      w2[4*i+0] = v.x; w2[4*i+1] = v.y; w2[4*i+2] = v.z; w2[4*i+3] = v.w;
    }
    float bias = bih[ln] + bhh[ln];
    const float* xb = X + (size_t)b * NL * NI;
#pragma unroll 4
    for (int t = 64 * wv; t < 64 * (wv + 1); ++t) {
      const float4* xr = (const float4*)(xb + t * NI);
      float x0 = bias, x1 = 0.f, x2 = 0.f, x3 = 0.f;
#pragma unroll
      for (int i = 0; i < 8; ++i) {
        float4 xv = xr[i];
        x0 += xv.x * w2[4*i+0]; x1 += xv.y * w2[4*i+1];
        x2 += xv.z * w2[4*i+2]; x3 += xv.w * w2[4*i+3];
      }
      xwT[ln * XS + t] = Kg * ((x0 + x1) + (x2 + x3));   // K pre-folded
    }
  }
  __syncthreads();

  // ---- Phase A (wave 0): LSTM. lane = 4*unit + gate_type (i,f,g,o).
  if (wv == 0) {
    __asm__ __volatile__("s_setprio 3");
    const int q = ln & 3;
    const int j = ln >> 2;
    const int gmem = q * 16 + j;
    const bool isg = (q == 2);
    const float Kg = isg ? 2.885390082f : -1.442695041f;
    const float CT = 2.885390082f;
    const float Av = isg ? -2.0f : (q == 0 ? CT : 1.0f);
    const float Bv = isg ? 1.0f : 0.0f;
    float w[NH];                               // K-scaled W_hh row
#pragma unroll
    for (int qq = 0; qq < 4; ++qq) {
      float4 v = *(const float4*)(Whh + gmem * NH + 4 * qq);
      w[4*qq+0] = Kg*v.x; w[4*qq+1] = Kg*v.y; w[4*qq+2] = Kg*v.z; w[4*qq+3] = Kg*v.w;
    }
    const float* xt = xwT + gmem * XS;
    // dual-role h write target (per-lane): q0 -> hcur copy, q1 -> column, else scratch
    float* wp;
    if (q == 0)      wp = hcur + j;
    else if (q == 1) wp = xwT + j * XS;        // advances by 1 float/step
    else             wp = hcur + 16 + (j * 2 + (q - 2));
    const int winc = (q == 1) ? 1 : 0;
    if (q == 0) hcur[j] = 0.0f;                // h[-1] = 0 (own-wave DS, in-order)
    float4 xq[4];                              // 16 steps of K-scaled xval in flight
#pragma unroll
    for (int i = 0; i < 4; ++i) xq[i] = *(const float4*)(xt + 4 * i);
    float cs = 0.0f;                           // cs = CT * c  (scaled cell state)
    for (int tb = 0; tb < NL; tb += 16) {
#pragma unroll
      for (int k = 0; k < 16; ++k) {
        int t = tb + k;
        // broadcast h[t-1]: 4 same-address ds_read_b128 (conflict-free)
        float4 h0 = *(const float4*)(hcur + 0);
        float4 h1 = *(const float4*)(hcur + 4);
        float4 h2 = *(const float4*)(hcur + 8);
        float4 h3 = *(const float4*)(hcur + 12);
        float xval = ((const float*)xq)[k];    // consume before refill
        if ((k & 3) == 3 && t + 16 < NL)
          xq[k >> 2] = *(const float4*)(xt + (t + 13));
        // 4-acc dot, FP association identical to previous rounds:
        float a0 = xval, a1 = 0.f, a2 = 0.f, a3 = 0.f;
        a0 += h0.x * w[0];  a1 += h0.y * w[1];  a2 += h0.z * w[2];  a3 += h0.w * w[3];
        a0 += h1.x * w[4];  a1 += h1.y * w[5];  a2 += h1.z * w[6];  a3 += h1.w * w[7];
        a0 += h2.x * w[8];  a1 += h2.y * w[9];  a2 += h2.z * w[10]; a3 += h2.w * w[11];
        a0 += h3.x * w[12]; a1 += h3.y * w[13]; a2 += h3.z * w[14]; a3 += h3.w * w[15];
        float acc = (a0 + a1) + (a2 + a3);
        float e = __builtin_amdgcn_exp2f(acc);
        float r = __builtin_amdgcn_rcpf(1.0f + e);
        float val = __builtin_fmaf(Av, r, Bv);
        float iv = QB<0x00>(val);              // already CT-scaled
        float fv = QB<0x55>(val);
        float gv = QB<0xAA>(val);
        float ov = QB<0xFF>(val);
        cs = __builtin_fmaf(fv, cs, iv * gv);  // scaled-c recurrence
        float e2 = __builtin_amdgcn_exp2f(cs);
        float tc = __builtin_fmaf(-2.0f, __builtin_amdgcn_rcpf(1.0f + e2), 1.0f);
        float hval = ov * tc;
        *wp = hval;                            // dual-role ds_write_b32
        wp += winc;
      }
      __asm__ __volatile__("" ::: "memory");
      if (ln == 0) *(volatile int*)&prog = tb + 15;
    }
    __asm__ __volatile__("s_setprio 0");
  }

  // ---- Phase B: streaming signature over this wave's segment.
  // seg: waves 1-6 -> segs 1-6; wave7 -> seg0 (prefix); wave0 -> seg7 (post-LSTM).
  int seg;
  if (wv >= 1 && wv <= 6) seg = wv;
  else if (wv == 7) seg = 0;
  else seg = 7;
  const int ts = segc(seg);
  const int te = segc(seg + 1);
  const int bi = ln & 15;
  const int hi = ln >> 4;

  float s3[4][16];
  float s2[4] = {0.f, 0.f, 0.f, 0.f};
#pragma unroll
  for (int m = 0; m < 4; ++m)
#pragma unroll
    for (int cc = 0; cc < 16; ++cc) s3[m][cc] = 0.f;

  int avail;
  while ((avail = *(volatile int*)&prog) < ts) __builtin_amdgcn_s_sleep(2);
  __asm__ __volatile__("" ::: "memory");

  float hA[16], hB[16];
  float hAb, hBb;
  float hAa[4], hBa[4], h0a[4];
#pragma unroll
  for (int cc = 0; cc < 16; ++cc) hA[cc] = xwT[cc * XS + ts];   // uniform reads
  hAb = xwT[bi * XS + ts];
#pragma unroll
  for (int m = 0; m < 4; ++m) { hAa[m] = xwT[(4 * m + hi) * XS + ts]; h0a[m] = hAa[m]; }

  auto SSTEP = [&](float (&hc16)[16], float& hcb, float (&hca)[4],
                   float (&hn16)[16], float& hnb, float (&hna)[4], int tn) {
#pragma unroll
    for (int cc = 0; cc < 16; ++cc) hn16[cc] = xwT[cc * XS + tn];
    hnb = xwT[bi * XS + tn];
    float d[16];
#pragma unroll
    for (int cc = 0; cc < 16; ++cc) d[cc] = hn16[cc] - hc16[cc];
    float db = hnb - hcb;
    float P[4];
#pragma unroll
    for (int m = 0; m < 4; ++m) {
      hna[m] = xwT[(4 * m + hi) * XS + tn];
      float da = hna[m] - hca[m];
      float s1 = hca[m] - h0a[m];                      // S1[a] pre-increment (telescoping)
      P[m] = s2[m] + db * (0.5f * s1 + 0.166666666667f * da);
      s2[m] += db * (s1 + 0.5f * da);                  // S2 += e2 + S1(x)e1
    }
#pragma unroll
    for (int m = 0; m < 4; ++m)
#pragma unroll
      for (int cc = 0; cc < 16; ++cc)
        s3[m][cc] += P[m] * d[cc];                     // S3 += e3 + S2(x)e1 + S1(x)e2
  };

  {
    int t = ts;
    for (; t + 2 <= te; t += 2) {
      int tn2 = t + 2;
      if (tn2 > avail) {
        while ((avail = *(volatile int*)&prog) < tn2) __builtin_amdgcn_s_sleep(2);
        __asm__ __volatile__("" ::: "memory");
      }
      SSTEP(hA, hAb, hAa, hB, hBb, hBa, t + 1);
      SSTEP(hB, hBb, hBa, hA, hAb, hAa, t + 2);
    }
    if (t < te) {
      if (te > avail) {
        while ((avail = *(volatile int*)&prog) < te) __builtin_amdgcn_s_sleep(2);
        __asm__ __volatile__("" ::: "memory");
      }
      SSTEP(hA, hAb, hAa, hB, hBb, hBa, t + 1);
    }
  }

  // ---- Phase C: prefix combine through one slot (want/have handshake).
  if (seg >= 1) {
    // producer: wait for my turn, publish my chunk state into the slot
    while (*(volatile int*)&want != seg) __builtin_amdgcn_s_sleep(8);
    __asm__ __volatile__("" ::: "memory");
#pragma unroll
    for (int m = 0; m < 4; ++m) slot[64 * m + ln] = s2[m];  // index == a*16+b
#pragma unroll
    for (int m = 0; m < 4; ++m)
#pragma unroll
      for (int cc = 0; cc < 16; ++cc)
        slot[256 + 64 * ln + ((m * 16 + cc) ^ (ln & 31))] = s3[m][cc];
    __asm__ __volatile__("s_waitcnt lgkmcnt(0)" ::: "memory");
    if (ln == 0) *(volatile int*)&have = seg;
  } else {
    // wave7: running prefix A=[0, segc(k)] folds in B=[segc(k), segc(k+1)]
    for (int k = 1; k <= 7; ++k) {
      if (ln == 0) *(volatile int*)&want = k;
      while (*(volatile int*)&have != k) __builtin_amdgcn_s_sleep(8);
      __asm__ __volatile__("" ::: "memory");
      const int ae_ = segc(k), be_ = segc(k + 1);
      float s1b[16];
#pragma unroll
      for (int cc = 0; cc < 16; ++cc)
        s1b[cc] = xwT[cc * XS + be_] - xwT[cc * XS + ae_];
      float s1bb = xwT[bi * XS + be_] - xwT[bi * XS + ae_];
      float s1aa[4];
#pragma unroll
      for (int m = 0; m < 4; ++m) {
        int a = 4 * m + hi;
        s1aa[m] = xwT[a * XS + ae_] - xwT[a * XS + 0];
      }
      float row[16];
#pragma unroll
      for (int cc = 0; cc < 16; ++cc) row[cc] = slot[bi * 16 + cc];
#pragma unroll
      for (int m = 0; m < 4; ++m) {
        float s2bo = slot[64 * m + ln];
#pragma unroll
        for (int cc = 0; cc < 16; ++cc)
          s3[m][cc] += slot[256 + 64 * ln + ((m * 16 + cc) ^ (ln & 31))]
                     + s2[m] * s1b[cc] + s1aa[m] * row[cc];   // uses OLD s2 (S2a)
        s2[m] += s2bo + s1aa[m] * s1bb;
      }
    }
    // ---- emit full signature to LDS (overlay dead xw rows >= 16)
    float* sigb = xwT + 16 * XS;
    if (ln < 16) sigb[ln] = xwT[ln * XS + 511] - xwT[ln * XS + 0];  // S1
#pragma unroll
    for (int m = 0; m < 4; ++m) sigb[16 + 64 * m + ln] = s2[m];     // S2: idx a*16+b
#pragma unroll
    for (int m = 0; m < 4; ++m) {                                    // S3: a*256+b*16+c
#pragma unroll
      for (int qq = 0; qq < 4; ++qq) {
        float4 v;
        v.x = s3[m][4*qq+0]; v.y = s3[m][4*qq+1]; v.z = s3[m][4*qq+2]; v.w = s3[m][4*qq+3];
        *(float4*)(sigb + 272 + 1024 * m + 256 * hi + 16 * bi + 4 * qq) = v;
      }
    }
  }
  __syncthreads();

  // ---- Phase D: FC. out[b][o] = sig·fc_w[o] + fc_b[o], all 512 threads.
  {
    const float* sigb = xwT + 16 * XS;
    float acc[10];
#pragma unroll
    for (int o = 0; o < 10; ++o) acc[o] = 0.f;
    for (int k = tid; k < SIGD; k += 512) {
      float s = sigb[k];
#pragma unroll
      for (int o = 0; o < 10; ++o) acc[o] += s * fcw[o * SIGD + k];
    }
#pragma unroll
    for (int o = 0; o < 10; ++o) {
      float v = acc[o];
#pragma unroll
      for (int off = 32; off > 0; off >>= 1) v += __shfl_down(v, off);
      if (ln == 0) red[wv * 10 + o] = v;
    }
    __syncthreads();
    if (tid < 10) {
      float s = fcb[tid];
#pragma unroll
      for (int w8 = 0; w8 < 8; ++w8) s += red[w8 * 10 + tid];
      out[b * 10 + tid] = s;
    }
  }
}

extern "C" void kernel_launch(void* const* d_in, const int* in_sizes, int n_in,
                              void* d_out, int out_size, void* d_ws, size_t ws_size,
                              hipStream_t stream) {
  const float* X   = (const float*)d_in[0];
  const float* Wih = (const float*)d_in[1];
  const float* Whh = (const float*)d_in[2];
  const float* bih = (const float*)d_in[3];
  const float* bhh = (const float*)d_in[4];
  const float* fcw = (const float*)d_in[5];
  const float* fcb = (const float*)d_in[6];
  float* out = (float*)d_out;
  k_main<<<NB, 512, 0, stream>>>(X, Wih, bih, bhh, Whh, fcw, fcb, out);
}

// Round 9
// 184.873 us; speedup vs baseline: 1.8712x; 1.0233x over previous
//
#include <hip/hip_runtime.h>

#define NB 256
#define NL 512
#define NI 32
#define NH 16
#define NG 64
#define SIGD 4368
#define XS 516   // xwT row stride (floats): pad -> strided access lands 2-way (free)

__device__ __forceinline__ float RL(float v, int lane) {
  return __builtin_bit_cast(float, __builtin_amdgcn_readlane(__builtin_bit_cast(int, v), lane));
}
template<int CTRL>
__device__ __forceinline__ float QB(float v) {
  // quad_perm broadcast within each 4-lane quad (VALU DPP, no LDS)
  return __builtin_bit_cast(float, __builtin_amdgcn_update_dpp(
      0, __builtin_bit_cast(int, v), CTRL, 0xF, 0xF, true));
}
__device__ __forceinline__ int segc(int k) {
  // segment cuts: seg0=[0,76] (prefix wave7), segs 1-6 (waves 1-6) cover
  // [76,511] -- wave6 streams to the very end (trails the LSTM by ~1 step;
  // round-3/5 proved streaming waves track the producer). No post-LSTM
  // solo segment for wave0 (solo rate 0.39us/step was the round-2 lesson).
  switch (k) {
    case 1: return 76;  case 2: return 149; case 3: return 221; case 4: return 294;
    case 5: return 366; case 6: return 439; case 7: return 511;
    default: return 0;
  }
}

// Round-3 structure (best measured: 128.2us) with the tail shortened:
// Phase 0: xw -> LDS transposed, PRE-SCALED by K_g. Phase A: wave0 LSTM
// (readlane broadcast, 4-acc dot, burst h-write, setprio 3). Phase B: waves
// 1-6 + wave7 stream signature segments against prog; wave6 runs to t=511.
// Phase C: wave7 prefix-combines k=1..6 through one LDS slot (want/have).
// Wave0 goes straight to the barrier after the LSTM. Phase D: FC.
__global__ __launch_bounds__(512, 1) void k_main(const float* __restrict__ X,
    const float* __restrict__ Wih, const float* __restrict__ bih,
    const float* __restrict__ bhh, const float* __restrict__ Whh,
    const float* __restrict__ fcw, const float* __restrict__ fcb,
    float* __restrict__ out) {
  __shared__ __align__(16) float xwT[NG * XS];    // 132,096 B
  __shared__ __align__(16) float slot[4352];      // 17,408 B (one chunk state)
  __shared__ __align__(16) float red[80];
  __shared__ int prog;
  __shared__ int want;
  __shared__ int have;
  int tid = threadIdx.x;
  int wv = tid >> 6;
  int ln = tid & 63;
  int b = blockIdx.x;

  if (tid == 0) { prog = -1; want = 0; have = 0; }

  // ---- Phase 0: xwT[g][t] = K_g * (X[b,t,:]·W_ih[g,:] + b_ih[g] + b_hh[g]).
  {
    const float Kg = (ln >= 32 && ln < 48) ? 2.885390082f : -1.442695041f;
    float w2[NI];
#pragma unroll
    for (int i = 0; i < 8; ++i) {
      float4 v = *(const float4*)(Wih + ln * NI + 4 * i);
      w2[4*i+0] = v.x; w2[4*i+1] = v.y; w2[4*i+2] = v.z; w2[4*i+3] = v.w;
    }
    float bias = bih[ln] + bhh[ln];
    const float* xb = X + (size_t)b * NL * NI;
#pragma unroll 4
    for (int t = 64 * wv; t < 64 * (wv + 1); ++t) {
      const float4* xr = (const float4*)(xb + t * NI);
      float x0 = bias, x1 = 0.f, x2 = 0.f, x3 = 0.f;
#pragma unroll
      for (int i = 0; i < 8; ++i) {
        float4 xv = xr[i];
        x0 += xv.x * w2[4*i+0]; x1 += xv.y * w2[4*i+1];
        x2 += xv.z * w2[4*i+2]; x3 += xv.w * w2[4*i+3];
      }
      xwT[ln * XS + t] = Kg * ((x0 + x1) + (x2 + x3));   // K pre-folded
    }
  }
  __syncthreads();

  // ---- Phase A (wave 0): LSTM, quad layout. lane = 4*unit + gate_type (i,f,g,o).
  if (wv == 0) {
    __asm__ __volatile__("s_setprio 3");
    const int q = ln & 3;
    const int j = ln >> 2;
    const int gmem = q * 16 + j;
    const bool isg = (q == 2);
    const float Kg = isg ? 2.885390082f : -1.442695041f;
    const float CT = 2.885390082f;
    const float Av = isg ? -2.0f : (q == 0 ? CT : 1.0f);
    const float Bv = isg ? 1.0f : 0.0f;
    float w[NH];                               // K-scaled W_hh row
#pragma unroll
    for (int qq = 0; qq < 4; ++qq) {
      float4 v = *(const float4*)(Whh + gmem * NH + 4 * qq);
      w[4*qq+0] = Kg*v.x; w[4*qq+1] = Kg*v.y; w[4*qq+2] = Kg*v.z; w[4*qq+3] = Kg*v.w;
    }
    const float* xt = xwT + gmem * XS;
    float* hdst = xwT + j * XS + 4 * q;        // burst-write base (all 64 lanes)
    float4 xq[4];                              // 16 steps of K-scaled xval in flight
#pragma unroll
    for (int i = 0; i < 4; ++i) xq[i] = *(const float4*)(xt + 4 * i);
    float cs = 0.0f, hval = 0.0f;              // cs = CT * c  (scaled cell state)
    float hst[4] = {0.f, 0.f, 0.f, 0.f};       // reg-buffered h (this lane's quarter)
    for (int tb = 0; tb < NL; tb += 16) {
#pragma unroll
      for (int k = 0; k < 16; ++k) {
        int t = tb + k;
        float hs[16];
#pragma unroll
        for (int u = 0; u < 16; ++u) hs[u] = RL(hval, 4 * u);
        float xval = ((const float*)xq)[k];    // consume before refill
        if ((k & 3) == 3 && t + 16 < NL)
          xq[k >> 2] = *(const float4*)(xt + (t + 13));
        float a0 = xval, a1 = 0.f, a2 = 0.f, a3 = 0.f;   // 4-acc dot (3 adds)
#pragma unroll
        for (int u = 0; u < 4; ++u) {
          a0 += hs[4*u+0] * w[4*u+0];
          a1 += hs[4*u+1] * w[4*u+1];
          a2 += hs[4*u+2] * w[4*u+2];
          a3 += hs[4*u+3] * w[4*u+3];
        }
        float acc = (a0 + a1) + (a2 + a3);
        float e = __builtin_amdgcn_exp2f(acc);
        float r = __builtin_amdgcn_rcpf(1.0f + e);
        float val = __builtin_fmaf(Av, r, Bv);
        float iv = QB<0x00>(val);              // already CT-scaled
        float fv = QB<0x55>(val);
        float gv = QB<0xAA>(val);
        float ov = QB<0xFF>(val);
        cs = __builtin_fmaf(fv, cs, iv * gv);  // scaled-c recurrence
        float e2 = __builtin_amdgcn_exp2f(cs);
        float tc = __builtin_fmaf(-2.0f, __builtin_amdgcn_rcpf(1.0f + e2), 1.0f);
        hval = ov * tc;
        hst[k & 3] = (q == (k >> 2)) ? hval : hst[k & 3];
      }
      // one ds_write_b128 covers the whole 16-step x 16-unit block
      float4 hv;
      hv.x = hst[0]; hv.y = hst[1]; hv.z = hst[2]; hv.w = hst[3];
      *(float4*)(hdst + tb) = hv;
      __asm__ __volatile__("" ::: "memory");
      if (ln == 0) *(volatile int*)&prog = tb + 15;
    }
    __asm__ __volatile__("s_setprio 0");
  } else {
    // ---- Phase B: streaming signature over this wave's segment.
    // seg: waves 1-6 -> segs 1-6 ([76,511]); wave7 -> seg0 ([0,76], prefix).
    const int seg = (wv == 7) ? 0 : wv;
    const int ts = segc(seg);
    const int te = segc(seg + 1);
    const int bi = ln & 15;
    const int hi = ln >> 4;

    float s3[4][16];
    float s2[4] = {0.f, 0.f, 0.f, 0.f};
#pragma unroll
    for (int m = 0; m < 4; ++m)
#pragma unroll
      for (int cc = 0; cc < 16; ++cc) s3[m][cc] = 0.f;

    int avail;
    while ((avail = *(volatile int*)&prog) < ts) __builtin_amdgcn_s_sleep(2);
    __asm__ __volatile__("" ::: "memory");

    float hA[16], hB[16];
    float hAb, hBb;
    float hAa[4], hBa[4], h0a[4];
#pragma unroll
    for (int cc = 0; cc < 16; ++cc) hA[cc] = xwT[cc * XS + ts];   // uniform reads
    hAb = xwT[bi * XS + ts];
#pragma unroll
    for (int m = 0; m < 4; ++m) { hAa[m] = xwT[(4 * m + hi) * XS + ts]; h0a[m] = hAa[m]; }

    auto SSTEP = [&](float (&hc16)[16], float& hcb, float (&hca)[4],
                     float (&hn16)[16], float& hnb, float (&hna)[4], int tn) {
#pragma unroll
      for (int cc = 0; cc < 16; ++cc) hn16[cc] = xwT[cc * XS + tn];
      hnb = xwT[bi * XS + tn];
      float d[16];
#pragma unroll
      for (int cc = 0; cc < 16; ++cc) d[cc] = hn16[cc] - hc16[cc];
      float db = hnb - hcb;
      float P[4];
#pragma unroll
      for (int m = 0; m < 4; ++m) {
        hna[m] = xwT[(4 * m + hi) * XS + tn];
        float da = hna[m] - hca[m];
        float s1 = hca[m] - h0a[m];                      // S1[a] pre-increment (telescoping)
        P[m] = s2[m] + db * (0.5f * s1 + 0.166666666667f * da);
        s2[m] += db * (s1 + 0.5f * da);                  // S2 += e2 + S1(x)e1
      }
#pragma unroll
      for (int m = 0; m < 4; ++m)
#pragma unroll
        for (int cc = 0; cc < 16; ++cc)
          s3[m][cc] += P[m] * d[cc];                     // S3 += e3 + S2(x)e1 + S1(x)e2
    };

    {
      int t = ts;
      for (; t + 2 <= te; t += 2) {
        int tn2 = t + 2;
        if (tn2 > avail) {
          while ((avail = *(volatile int*)&prog) < tn2) __builtin_amdgcn_s_sleep(2);
          __asm__ __volatile__("" ::: "memory");
        }
        SSTEP(hA, hAb, hAa, hB, hBb, hBa, t + 1);
        SSTEP(hB, hBb, hBa, hA, hAb, hAa, t + 2);
      }
      if (t < te) {
        if (te > avail) {
          while ((avail = *(volatile int*)&prog) < te) __builtin_amdgcn_s_sleep(2);
          __asm__ __volatile__("" ::: "memory");
        }
        SSTEP(hA, hAb, hAa, hB, hBb, hBa, t + 1);
      }
    }

    // ---- Phase C: prefix combine through one slot (want/have handshake).
    if (seg >= 1) {
      // producer: wait for my turn, publish my chunk state into the slot
      while (*(volatile int*)&want != seg) __builtin_amdgcn_s_sleep(8);
      __asm__ __volatile__("" ::: "memory");
#pragma unroll
      for (int m = 0; m < 4; ++m) slot[64 * m + ln] = s2[m];  // index == a*16+b
#pragma unroll
      for (int m = 0; m < 4; ++m)
#pragma unroll
        for (int cc = 0; cc < 16; ++cc)
          slot[256 + 64 * ln + ((m * 16 + cc) ^ (ln & 31))] = s3[m][cc];
      __asm__ __volatile__("s_waitcnt lgkmcnt(0)" ::: "memory");
      if (ln == 0) *(volatile int*)&have = seg;
    } else {
      // wave7: running prefix A=[0, segc(k)] folds in B=[segc(k), segc(k+1)]
      for (int k = 1; k <= 6; ++k) {
        if (ln == 0) *(volatile int*)&want = k;
        while (*(volatile int*)&have != k) __builtin_amdgcn_s_sleep(8);
        __asm__ __volatile__("" ::: "memory");
        const int ae_ = segc(k), be_ = segc(k + 1);
        float s1b[16];
#pragma unroll
        for (int cc = 0; cc < 16; ++cc)
          s1b[cc] = xwT[cc * XS + be_] - xwT[cc * XS + ae_];
        float s1bb = xwT[bi * XS + be_] - xwT[bi * XS + ae_];
        float s1aa[4];
#pragma unroll
        for (int m = 0; m < 4; ++m) {
          int a = 4 * m + hi;
          s1aa[m] = xwT[a * XS + ae_] - xwT[a * XS + 0];
        }
        float row[16];
#pragma unroll
        for (int cc = 0; cc < 16; ++cc) row[cc] = slot[bi * 16 + cc];
#pragma unroll
        for (int m = 0; m < 4; ++m) {
          float s2bo = slot[64 * m + ln];
#pragma unroll
          for (int cc = 0; cc < 16; ++cc)
            s3[m][cc] += slot[256 + 64 * ln + ((m * 16 + cc) ^ (ln & 31))]
                       + s2[m] * s1b[cc] + s1aa[m] * row[cc];   // uses OLD s2 (S2a)
          s2[m] += s2bo + s1aa[m] * s1bb;
        }
      }
      // ---- emit full signature to LDS (overlay dead xw rows >= 16)
      float* sigb = xwT + 16 * XS;
      if (ln < 16) sigb[ln] = xwT[ln * XS + 511] - xwT[ln * XS + 0];  // S1
#pragma unroll
      for (int m = 0; m < 4; ++m) sigb[16 + 64 * m + ln] = s2[m];     // S2: idx a*16+b
#pragma unroll
      for (int m = 0; m < 4; ++m) {                                    // S3: a*256+b*16+c
#pragma unroll
        for (int qq = 0; qq < 4; ++qq) {
          float4 v;
          v.x = s3[m][4*qq+0]; v.y = s3[m][4*qq+1]; v.z = s3[m][4*qq+2]; v.w = s3[m][4*qq+3];
          *(float4*)(sigb + 272 + 1024 * m + 256 * hi + 16 * bi + 4 * qq) = v;
        }
      }
    }
  }
  __syncthreads();

  // ---- Phase D: FC. out[b][o] = sig·fc_w[o] + fc_b[o], all 512 threads.
  {
    const float* sigb = xwT + 16 * XS;
    float acc[10];
#pragma unroll
    for (int o = 0; o < 10; ++o) acc[o] = 0.f;
    for (int k = tid; k < SIGD; k += 512) {
      float s = sigb[k];
#pragma unroll
      for (int o = 0; o < 10; ++o) acc[o] += s * fcw[o * SIGD + k];
    }
#pragma unroll
    for (int o = 0; o < 10; ++o) {
      float v = acc[o];
#pragma unroll
      for (int off = 32; off > 0; off >>= 1) v += __shfl_down(v, off);
      if (ln == 0) red[wv * 10 + o] = v;
    }
    __syncthreads();
    if (tid < 10) {
      float s = fcb[tid];
#pragma unroll
      for (int w8 = 0; w8 < 8; ++w8) s += red[w8 * 10 + tid];
      out[b * 10 + tid] = s;
    }
  }
}

extern "C" void kernel_launch(void* const* d_in, const int* in_sizes, int n_in,
                              void* d_out, int out_size, void* d_ws, size_t ws_size,
                              hipStream_t stream) {
  const float* X   = (const float*)d_in[0];
  const float* Wih = (const float*)d_in[1];
  const float* Whh = (const float*)d_in[2];
  const float* bih = (const float*)d_in[3];
  const float* bhh = (const float*)d_in[4];
  const float* fcw = (const float*)d_in[5];
  const float* fcb = (const float*)d_in[6];
  float* out = (float*)d_out;
  k_main<<<NB, 512, 0, stream>>>(X, Wih, bih, bhh, Whh, fcw, fcb, out);
}